// Round 2
// baseline (630.797 us; speedup 1.0000x reference)
//
#include <hip/hip_runtime.h>
#include <cmath>

// B=8, C=64, H=256, W=256, k=3, pad=1 (H only)
#define HW 65536
#define NPER 524288   // B*H*W per channel for BN

typedef __attribute__((ext_vector_type(8))) short bf16x8;   // 8 bf16 = 4 VGPRs
typedef __attribute__((ext_vector_type(4))) float f32x4;

__device__ __forceinline__ unsigned short f2bf(float f) {
  unsigned u = __float_as_uint(f);
  u += 0x7fffu + ((u >> 16) & 1u);        // round-to-nearest-even
  return (unsigned short)(u >> 16);
}

// ws layout (floats): sums @0 (128) | wfT @128 (2304: [c*3+kh][12], 9 used)
//                     wtB @2432 as ushort (12288: [o][kh*64+c] bf16)
#define SUMS_OFF 0
#define WFT_OFF  128
#define WTB_OFF  2432

__global__ __launch_bounds__(256) void prep_wts(
    const float* __restrict__ w_off, const float* __restrict__ w_dcn,
    float* __restrict__ wfT, unsigned short* __restrict__ wtB) {
  int i = blockIdx.x * 256 + threadIdx.x;
  if (i < 12288) {
    int o = i / 192, j = i - o * 192, kh = j >> 6, c = j & 63;
    wtB[i] = f2bf(w_dcn[(o * 64 + c) * 3 + kh]);
  }
  if (i < 1728) {
    int o = i % 9, ck = i / 9, c = ck / 3, kh = ck % 3;
    wfT[ck * 12 + o] = w_off[(o * 64 + c) * 3 + kh];
  }
}

// Fused: offset-conv (VALU, fp32) -> bilinear sample*mask -> S tile (bf16, LDS)
// -> MFMA einsum (64 pix x 64 out x K=192) -> +b_dcn -> coalesced store.
// Block = 256 thr = 4 waves = 64 pixels (one b, one h, 64 consecutive w).
__global__ __launch_bounds__(256) void dcn_fused(
    const float* __restrict__ x, const float* __restrict__ wfT,
    const float* __restrict__ b_off, const unsigned short* __restrict__ wtB,
    const float* __restrict__ b_dcn, float* __restrict__ out) {
  // sA: bf16 [64][200] (stride 200 => 100 words = 4 mod 32 -> 2-way max, free)
  // sOut: f32 [64][65] aliases sA (65 = 1 mod 32 -> 2-way max)
  // sOM: f32 [64][37] offset-conv partials (37 = 5 mod 32 -> conflict-free-ish)
  __shared__ __align__(16) unsigned char lds[25600 + 9472];
  short* sA   = (short*)lds;
  float* sOut = (float*)lds;
  float* sOM  = (float*)(lds + 25600);

  const int t = threadIdx.x;
  const int lane = t & 63;
  const int cq = t >> 6;           // wave id; also channel-quarter for sampling
  const int p = lane;              // pixel within tile

  // XCD swizzle: each XCD (blk&7) owns a contiguous (b,h) range for L2 reuse
  int g = ((blockIdx.x & 7) << 10) | (blockIdx.x >> 3);
  int b = g >> 10;
  int rem = g & 1023;
  int h = rem >> 2;
  int w0 = (rem & 3) << 6;
  int w = w0 + p;

  const float* xb = x + ((size_t)b << 6) * HW;
  const int c0 = cq << 4;

  // ---- Phase 1: offset-conv partials over c in [c0, c0+16) ----
  float om[9];
#pragma unroll
  for (int o = 0; o < 9; ++o) om[o] = 0.f;
  for (int ci = 0; ci < 16; ++ci) {
    int c = c0 + ci;
    const float* xc = xb + (size_t)c * HW + w;
#pragma unroll
    for (int kh = 0; kh < 3; ++kh) {
      int hr = h + kh - 1;                    // x row (xp row - 1)
      int hc = min(max(hr, 0), 255);
      float v = xc[hc * 256];
      v = (hr >= 0 && hr < 256) ? v : 0.f;
      const float* wr = wfT + (c * 3 + kh) * 12;   // wave-uniform -> s_load
#pragma unroll
      for (int o = 0; o < 9; ++o) om[o] = fmaf(v, wr[o], om[o]);
    }
  }
#pragma unroll
  for (int o = 0; o < 9; ++o) sOM[p * 37 + cq * 9 + o] = om[o];
  __syncthreads();
#pragma unroll
  for (int o = 0; o < 9; ++o)
    om[o] = b_off[o] + sOM[p * 37 + o] + sOM[p * 37 + 9 + o] +
            sOM[p * 37 + 18 + o] + sOM[p * 37 + 27 + o];

  // ---- Phase 2: bilinear sample * mask -> S[p][kh*64+c] bf16 in LDS ----
#pragma unroll
  for (int kh = 0; kh < 3; ++kh) {
    float m = 1.f / (1.f + __expf(-om[6 + kh]));
    float yf = (float)(h + kh) + om[kh];      // xp coords
    float xf = (float)w + om[3 + kh];
    float y0f = floorf(yf), x0f = floorf(xf);
    int iy0 = (int)y0f, ix0 = (int)x0f;
    float wy1 = yf - y0f, wy0 = 1.f - wy1;
    float wx1 = xf - x0f, wx0 = 1.f - wx1;
    int r0 = iy0 - 1, r1 = iy0, g0 = ix0, g1 = ix0 + 1;   // x-array rows/cols
    bool vr0 = (r0 >= 0) & (r0 < 256), vr1 = (r1 >= 0) & (r1 < 256);
    bool vc0 = (g0 >= 0) & (g0 < 256), vc1 = (g1 >= 0) & (g1 < 256);
    float w00 = (vr0 & vc0) ? wy0 * wx0 * m : 0.f;
    float w01 = (vr0 & vc1) ? wy0 * wx1 * m : 0.f;
    float w10 = (vr1 & vc0) ? wy1 * wx0 * m : 0.f;
    float w11 = (vr1 & vc1) ? wy1 * wx1 * m : 0.f;
    int cr0 = min(max(r0, 0), 255), cr1 = min(max(r1, 0), 255);
    int cg0 = min(max(g0, 0), 255), cg1 = min(max(g1, 0), 255);
    int o00 = cr0 * 256 + cg0, o01 = cr0 * 256 + cg1;
    int o10 = cr1 * 256 + cg0, o11 = cr1 * 256 + cg1;
#pragma unroll
    for (int half = 0; half < 2; ++half) {
      bf16x8 pk;
#pragma unroll
      for (int ci = 0; ci < 8; ++ci) {
        const float* xc = xb + (size_t)(c0 + half * 8 + ci) * HW;
        float s = xc[o00] * w00 + xc[o01] * w01 + xc[o10] * w10 + xc[o11] * w11;
        pk[ci] = (short)f2bf(s);
      }
      *(bf16x8*)(sA + p * 200 + kh * 64 + c0 + half * 8) = pk;
    }
  }

  // B-fragments (this wave's 16 output channels) + bias, loaded pre-barrier
  const int nrow = (cq << 4) | (lane & 15);   // output channel o
  const int kgrp = (lane >> 4) << 3;          // k offset: (lane>>4)*8
  bf16x8 Bf[6];
#pragma unroll
  for (int kt = 0; kt < 6; ++kt)
    Bf[kt] = *(const bf16x8*)(wtB + nrow * 192 + kt * 32 + kgrp);
  float bdc = b_dcn[nrow];
  __syncthreads();

  // ---- Phase 3: MFMA 64x64 += S(64x192) * W(192x64) ----
  f32x4 acc[4];
#pragma unroll
  for (int mt = 0; mt < 4; ++mt) acc[mt] = (f32x4){0.f, 0.f, 0.f, 0.f};
#pragma unroll
  for (int kt = 0; kt < 6; ++kt) {
#pragma unroll
    for (int mt = 0; mt < 4; ++mt) {
      bf16x8 Af = *(const bf16x8*)(sA + (mt * 16 + (lane & 15)) * 200 +
                                   kt * 32 + kgrp);
      acc[mt] = __builtin_amdgcn_mfma_f32_16x16x32_bf16(Af, Bf[kt], acc[mt],
                                                        0, 0, 0);
    }
  }
  __syncthreads();   // sA dead; reuse as sOut

  // ---- Phase 4: C frags (col=lane&15, row=(lane>>4)*4+reg) -> sOut[p][o] ----
#pragma unroll
  for (int mt = 0; mt < 4; ++mt) {
    int prow = mt * 16 + ((lane >> 4) << 2);
#pragma unroll
    for (int r = 0; r < 4; ++r)
      sOut[(prow + r) * 65 + nrow] = acc[mt][r] + bdc;
  }
  __syncthreads();

  // ---- Phase 5: coalesced store (lane = w) ----
  float* ob = out + ((size_t)b << 6) * HW + h * 256 + w0;
#pragma unroll
  for (int i = 0; i < 16; ++i) {
    int o = (cq << 4) + i;
    ob[(size_t)o * HW + p] = sOut[p * 65 + o];
  }
}

__global__ __launch_bounds__(256) void bn_sums(
    const float* __restrict__ out, float* __restrict__ sums) {
  int pl = blockIdx.x;                 // plane = b*64+o
  int o = pl & 63;
  const float4* base = (const float4*)(out + (size_t)pl * HW);
  float s = 0.f, q = 0.f;
  for (int i = threadIdx.x; i < 16384; i += 256) {
    float4 v = base[i];
    s += v.x + v.y + v.z + v.w;
    q += v.x * v.x + v.y * v.y + v.z * v.z + v.w * v.w;
  }
#pragma unroll
  for (int off = 32; off > 0; off >>= 1) {
    s += __shfl_down(s, off);
    q += __shfl_down(q, off);
  }
  __shared__ float ls[4], lq[4];
  int wid = threadIdx.x >> 6, ln = threadIdx.x & 63;
  if (ln == 0) { ls[wid] = s; lq[wid] = q; }
  __syncthreads();
  if (threadIdx.x == 0) {
    atomicAdd(&sums[o], ls[0] + ls[1] + ls[2] + ls[3]);
    atomicAdd(&sums[64 + o], lq[0] + lq[1] + lq[2] + lq[3]);
  }
}

__global__ __launch_bounds__(256) void bn_apply(
    float* __restrict__ out, const float* __restrict__ sums,
    const float* __restrict__ gamma, const float* __restrict__ beta) {
  int pl = blockIdx.x;
  int o = pl & 63;
  float mean = sums[o] * (1.f / (float)NPER);
  float var = sums[64 + o] * (1.f / (float)NPER) - mean * mean;
  float inv = rsqrtf(var + 1e-5f);
  float sc = gamma[o] * inv;
  float sh = beta[o] - mean * sc;
  float4* base = (float4*)(out + (size_t)pl * HW);
  for (int i = threadIdx.x; i < 16384; i += 256) {
    float4 v = base[i];
    v.x = fmaxf(fmaf(v.x, sc, sh), 0.f);
    v.y = fmaxf(fmaf(v.y, sc, sh), 0.f);
    v.z = fmaxf(fmaf(v.z, sc, sh), 0.f);
    v.w = fmaxf(fmaf(v.w, sc, sh), 0.f);
    base[i] = v;
  }
}

extern "C" void kernel_launch(void* const* d_in, const int* in_sizes, int n_in,
                              void* d_out, int out_size, void* d_ws, size_t ws_size,
                              hipStream_t stream) {
  const float* x     = (const float*)d_in[0];
  const float* w_off = (const float*)d_in[1];
  const float* b_off = (const float*)d_in[2];
  const float* w_dcn = (const float*)d_in[3];
  const float* b_dcn = (const float*)d_in[4];
  const float* gamma = (const float*)d_in[5];
  const float* beta  = (const float*)d_in[6];
  float* out = (float*)d_out;
  float* ws  = (float*)d_ws;

  float* sums = ws + SUMS_OFF;
  float* wfT  = ws + WFT_OFF;
  unsigned short* wtB = (unsigned short*)(ws + WTB_OFF);

  hipMemsetAsync(sums, 0, 128 * sizeof(float), stream);
  prep_wts<<<48, 256, 0, stream>>>(w_off, w_dcn, wfT, wtB);
  dcn_fused<<<8192, 256, 0, stream>>>(x, wfT, b_off, wtB, b_dcn, out);
  bn_sums<<<512, 256, 0, stream>>>(out, sums);
  bn_apply<<<512, 256, 0, stream>>>(out, sums, gamma, beta);
}

// Round 3
// 624.469 us; speedup vs baseline: 1.0101x; 1.0101x over previous
//
#include <hip/hip_runtime.h>
#include <cmath>

// B=8, C=64, H=256, W=256, k=3, pad=1 (H only)
#define HW 65536
#define NPER 524288   // B*H*W per channel for BN
#define NBLK 8192     // dcn_fused grid

typedef __attribute__((ext_vector_type(8))) short bf16x8;   // 8 bf16 = 4 VGPRs
typedef __attribute__((ext_vector_type(4))) float f32x4;

__device__ __forceinline__ unsigned short f2bf(float f) {
  unsigned u = __float_as_uint(f);
  u += 0x7fffu + ((u >> 16) & 1u);        // round-to-nearest-even
  return (unsigned short)(u >> 16);
}

// ws layout (floats):
//  sums  @0     : 128 (mean/var accumulators, written by reduce_sums)
//  wfT   @128   : 2304  [c*3+kh][12] (9 used)
//  wtB   @2432  : 12288 ushort = 6144 floats  [o][kh*64+c] bf16
//  part  @8576  : [128][8192] per-block channel sum/sumsq partials
#define SUMS_OFF 0
#define WFT_OFF  128
#define WTB_OFF  2432
#define PART_OFF 8576

__global__ __launch_bounds__(256) void prep_wts(
    const float* __restrict__ w_off, const float* __restrict__ w_dcn,
    float* __restrict__ wfT, unsigned short* __restrict__ wtB) {
  int i = blockIdx.x * 256 + threadIdx.x;
  if (i < 12288) {
    int o = i / 192, j = i - o * 192, kh = j >> 6, c = j & 63;
    wtB[i] = f2bf(w_dcn[(o * 64 + c) * 3 + kh]);
  }
  if (i < 1728) {
    int o = i % 9, ck = i / 9, c = ck / 3, kh = ck % 3;
    wfT[ck * 12 + o] = w_off[(o * 64 + c) * 3 + kh];
  }
}

// Fused: offset-conv -> bilinear sample*mask -> S tile (bf16, LDS) -> MFMA
// einsum -> +b_dcn -> BN partial sums -> coalesced store of pre-BN out.
// Block = 256 thr = 4 waves = 64 pixels (one b, one h, 64 consecutive w).
// Each wave owns 16 output channels; sampling split 16 input ch per wave.
__global__ __launch_bounds__(256, 4) void dcn_fused(
    const float* __restrict__ x, const float* __restrict__ wfT,
    const float* __restrict__ b_off, const unsigned short* __restrict__ wtB,
    const float* __restrict__ b_dcn, float* __restrict__ out,
    float* __restrict__ part) {
  // sA: bf16 [64][200]; sOut: f32 [64][65] aliases sA; sOM: f32 [64][37]
  __shared__ __align__(16) unsigned char lds[25600 + 9472];
  short* sA   = (short*)lds;
  float* sOut = (float*)lds;
  float* sOM  = (float*)(lds + 25600);

  const int t = threadIdx.x;
  const int lane = t & 63;
  const int cq = t >> 6;           // wave id = channel-quarter for sampling
  const int p = lane;              // pixel within tile

  // XCD swizzle: each XCD (blk&7) owns a contiguous (b,h) range
  int g = ((blockIdx.x & 7) << 10) | (blockIdx.x >> 3);
  int b = g >> 10;
  int rem = g & 1023;
  int h = rem >> 2;
  int w0 = (rem & 3) << 6;
  int w = w0 + p;

  const float* xb = x + ((size_t)b << 6) * HW;
  const int c0 = cq << 4;

  // ---- Phase 1: offset-conv partials, batched loads first ----
  float xv[3][16];
  const float* xw = xb + w;
#pragma unroll
  for (int kh = 0; kh < 3; ++kh) {
    int hr = h + kh - 1;                      // x row (xp row - 1)
    int hc = min(max(hr, 0), 255);
    const float* pr = xw + hc * 256;
#pragma unroll
    for (int ci = 0; ci < 16; ++ci)
      xv[kh][ci] = pr[(size_t)(c0 + ci) * HW];
  }
  float vm0 = (h == 0) ? 0.f : 1.f;           // zero-pad rows of xp
  float vm2 = (h == 255) ? 0.f : 1.f;
#pragma unroll
  for (int ci = 0; ci < 16; ++ci) { xv[0][ci] *= vm0; xv[2][ci] *= vm2; }

  float om[9];
#pragma unroll
  for (int o = 0; o < 9; ++o) om[o] = 0.f;
#pragma unroll
  for (int ci = 0; ci < 16; ++ci) {
    int c = c0 + ci;
#pragma unroll
    for (int kh = 0; kh < 3; ++kh) {
      const float* wr = wfT + (c * 3 + kh) * 12;   // wave-uniform -> s_load
      float v = xv[kh][ci];
#pragma unroll
      for (int o = 0; o < 9; ++o) om[o] = fmaf(v, wr[o], om[o]);
    }
  }
#pragma unroll
  for (int o = 0; o < 9; ++o) sOM[p * 37 + cq * 9 + o] = om[o];
  __syncthreads();
#pragma unroll
  for (int o = 0; o < 9; ++o)
    om[o] = b_off[o] + sOM[p * 37 + o] + sOM[p * 37 + 9 + o] +
            sOM[p * 37 + 18 + o] + sOM[p * 37 + 27 + o];

  // ---- Phase 2: bilinear sample * mask -> S[p][kh*64+c] bf16 in LDS ----
#pragma unroll
  for (int kh = 0; kh < 3; ++kh) {
    float m = 1.f / (1.f + __expf(-om[6 + kh]));
    float yf = (float)(h + kh) + om[kh];      // xp coords
    float xf = (float)w + om[3 + kh];
    float y0f = floorf(yf), x0f = floorf(xf);
    int iy0 = (int)y0f, ix0 = (int)x0f;
    float wy1 = yf - y0f, wy0 = 1.f - wy1;
    float wx1 = xf - x0f, wx0 = 1.f - wx1;
    int r0 = iy0 - 1, r1 = iy0, g0 = ix0, g1 = ix0 + 1;   // x rows/cols
    bool vr0 = (r0 >= 0) & (r0 < 256), vr1 = (r1 >= 0) & (r1 < 256);
    bool vc0 = (g0 >= 0) & (g0 < 256), vc1 = (g1 >= 0) & (g1 < 256);
    float w00 = (vr0 & vc0) ? wy0 * wx0 * m : 0.f;
    float w01 = (vr0 & vc1) ? wy0 * wx1 * m : 0.f;
    float w10 = (vr1 & vc0) ? wy1 * wx0 * m : 0.f;
    float w11 = (vr1 & vc1) ? wy1 * wx1 * m : 0.f;
    int cr0 = min(max(r0, 0), 255), cr1 = min(max(r1, 0), 255);
    int cg0 = min(max(g0, 0), 255), cg1 = min(max(g1, 0), 255);
    int o00 = cr0 * 256 + cg0, o01 = cr0 * 256 + cg1;
    int o10 = cr1 * 256 + cg0, o11 = cr1 * 256 + cg1;

    // Batch all 64 tap loads before any use (MLP!)
    float tv[4][16];
#pragma unroll
    for (int ci = 0; ci < 16; ++ci) {
      const float* xc = xb + (size_t)(c0 + ci) * HW;
      tv[0][ci] = xc[o00];
      tv[1][ci] = xc[o01];
      tv[2][ci] = xc[o10];
      tv[3][ci] = xc[o11];
    }
#pragma unroll
    for (int half = 0; half < 2; ++half) {
      bf16x8 pk;
#pragma unroll
      for (int j = 0; j < 8; ++j) {
        int ci = half * 8 + j;
        float s = tv[0][ci] * w00 + tv[1][ci] * w01 +
                  tv[2][ci] * w10 + tv[3][ci] * w11;
        pk[j] = (short)f2bf(s);
      }
      *(bf16x8*)(sA + p * 200 + kh * 64 + c0 + half * 8) = pk;
    }
  }

  // B-fragments (this wave's 16 output channels) + bias
  const int nrow = (cq << 4) | (lane & 15);   // output channel o
  const int kgrp = (lane >> 4) << 3;          // k offset
  bf16x8 Bf[6];
#pragma unroll
  for (int kt = 0; kt < 6; ++kt)
    Bf[kt] = *(const bf16x8*)(wtB + nrow * 192 + kt * 32 + kgrp);
  float bdc = b_dcn[nrow];
  __syncthreads();

  // ---- Phase 3: MFMA 64x64 += S(64x192) * W(192x64) ----
  f32x4 acc[4];
#pragma unroll
  for (int mt = 0; mt < 4; ++mt) acc[mt] = (f32x4){0.f, 0.f, 0.f, 0.f};
#pragma unroll
  for (int kt = 0; kt < 6; ++kt) {
#pragma unroll
    for (int mt = 0; mt < 4; ++mt) {
      bf16x8 Af = *(const bf16x8*)(sA + (mt * 16 + (lane & 15)) * 200 +
                                   kt * 32 + kgrp);
      acc[mt] = __builtin_amdgcn_mfma_f32_16x16x32_bf16(Af, Bf[kt], acc[mt],
                                                        0, 0, 0);
    }
  }
  __syncthreads();   // sA dead; reuse as sOut

  // ---- Phase 4: C frags (col=lane&15, row=(lane>>4)*4+reg) -> sOut,
  //               plus per-channel BN partial sums from registers ----
  float s1 = 0.f, s2 = 0.f;
#pragma unroll
  for (int mt = 0; mt < 4; ++mt) {
    int prow = mt * 16 + ((lane >> 4) << 2);
#pragma unroll
    for (int r = 0; r < 4; ++r) {
      float v = acc[mt][r] + bdc;
      sOut[(prow + r) * 65 + nrow] = v;
      s1 += v;
      s2 += v * v;
    }
  }
  // lanes {L, L+16, L+32, L+48} share channel nrow -> xor-reduce
  s1 += __shfl_xor(s1, 16); s1 += __shfl_xor(s1, 32);
  s2 += __shfl_xor(s2, 16); s2 += __shfl_xor(s2, 32);
  if ((lane >> 4) == 0) {
    part[(size_t)nrow * NBLK + blockIdx.x] = s1;
    part[(size_t)(64 + nrow) * NBLK + blockIdx.x] = s2;
  }
  __syncthreads();

  // ---- Phase 5: coalesced store (lane = w) ----
  float* ob = out + ((size_t)b << 6) * HW + h * 256 + w0;
#pragma unroll
  for (int i = 0; i < 16; ++i) {
    int o = (cq << 4) + i;
    ob[(size_t)o * HW + p] = sOut[p * 65 + o];
  }
}

// part[j][0..8191] -> sums[j], j in [0,128)
__global__ __launch_bounds__(256) void reduce_sums(
    const float* __restrict__ part, float* __restrict__ sums) {
  int j = blockIdx.x;
  const float4* p4 = (const float4*)(part + (size_t)j * NBLK);
  float s = 0.f;
  for (int i = threadIdx.x; i < NBLK / 4; i += 256) {
    float4 v = p4[i];
    s += v.x + v.y + v.z + v.w;
  }
#pragma unroll
  for (int off = 32; off > 0; off >>= 1) s += __shfl_down(s, off);
  __shared__ float ls[4];
  int wid = threadIdx.x >> 6, ln = threadIdx.x & 63;
  if (ln == 0) ls[wid] = s;
  __syncthreads();
  if (threadIdx.x == 0) sums[j] = ls[0] + ls[1] + ls[2] + ls[3];
}

// In-place: out = relu((out-mean)*rsqrt(var+eps)*gamma + beta)
__global__ __launch_bounds__(256) void bn_apply(
    float* __restrict__ out, const float* __restrict__ sums,
    const float* __restrict__ gamma, const float* __restrict__ beta) {
  int blk = blockIdx.x;            // 2048 = 512 planes x 4 quarters
  int pl = blk >> 2, q = blk & 3;
  int o = pl & 63;
  float mean = sums[o] * (1.f / (float)NPER);
  float var = sums[64 + o] * (1.f / (float)NPER) - mean * mean;
  float inv = rsqrtf(var + 1e-5f);
  float sc = gamma[o] * inv;
  float sh = beta[o] - mean * sc;
  float4* base = (float4*)(out + (size_t)pl * HW + q * 16384);
  for (int i = threadIdx.x; i < 4096; i += 256) {
    float4 v = base[i];
    v.x = fmaxf(fmaf(v.x, sc, sh), 0.f);
    v.y = fmaxf(fmaf(v.y, sc, sh), 0.f);
    v.z = fmaxf(fmaf(v.z, sc, sh), 0.f);
    v.w = fmaxf(fmaf(v.w, sc, sh), 0.f);
    base[i] = v;
  }
}

extern "C" void kernel_launch(void* const* d_in, const int* in_sizes, int n_in,
                              void* d_out, int out_size, void* d_ws, size_t ws_size,
                              hipStream_t stream) {
  const float* x     = (const float*)d_in[0];
  const float* w_off = (const float*)d_in[1];
  const float* b_off = (const float*)d_in[2];
  const float* w_dcn = (const float*)d_in[3];
  const float* b_dcn = (const float*)d_in[4];
  const float* gamma = (const float*)d_in[5];
  const float* beta  = (const float*)d_in[6];
  float* out = (float*)d_out;
  float* ws  = (float*)d_ws;

  float* sums = ws + SUMS_OFF;
  float* wfT  = ws + WFT_OFF;
  unsigned short* wtB = (unsigned short*)(ws + WTB_OFF);
  float* part = ws + PART_OFF;

  prep_wts<<<48, 256, 0, stream>>>(w_off, w_dcn, wfT, wtB);
  dcn_fused<<<NBLK, 256, 0, stream>>>(x, wfT, b_off, wtB, b_dcn, out, part);
  reduce_sums<<<128, 256, 0, stream>>>(part, sums);
  bn_apply<<<2048, 256, 0, stream>>>(out, sums, gamma, beta);
}

// Round 4
// 466.818 us; speedup vs baseline: 1.3513x; 1.3377x over previous
//
#include <hip/hip_runtime.h>
#include <cmath>

// B=8, C=64, H=256, W=256, k=3, pad=1 (H only)
#define HW 65536
#define NPER 524288   // B*H*W per channel for BN
#define NBLK 8192     // total fused block-slots (4 launches x 2048)

typedef _Float16 f16;
typedef __attribute__((ext_vector_type(8))) _Float16 f16x8;
typedef __attribute__((ext_vector_type(4))) float f32x4;

__device__ __forceinline__ f16x8 splat8(float v) {
  f16 h = (f16)v;
  f16x8 r = {h, h, h, h, h, h, h, h};
  return r;
}

// ws layout (floats):
//  sums  @0       : 128
//  wtO   @128     : 3072 halves = 1536 floats   [16 n][192 k] fp16 (n>=9 zeroed)
//  wtH   @1664    : 12288 halves = 6144 floats  [64 o][192 k] fp16
//  part  @7808    : 128*8192 per-block BN partials
//  xT    @1056384 : 2 batches * 65536 * 64 halves = 4194304 floats (16.8 MB)
#define SUMS_OFF 0
#define WTO_OFF  128
#define WTH_OFF  1664
#define PART_OFF 7808
#define XT_OFF   1056384

__global__ __launch_bounds__(256) void prep_wts(
    const float* __restrict__ w_off, const float* __restrict__ w_dcn,
    f16* __restrict__ wtO, f16* __restrict__ wtH) {
  int i = blockIdx.x * 256 + threadIdx.x;
  if (i < 12288) {
    int o = i / 192, k = i - o * 192, kh = k >> 6, c = k & 63;
    wtH[i] = (f16)w_dcn[(o * 64 + c) * 3 + kh];
  }
  if (i < 3072) {
    int n = i / 192, k = i - n * 192, kh = k >> 6, c = k & 63;
    wtO[i] = (n < 9) ? (f16)w_off[(n * 64 + c) * 3 + kh] : (f16)0.f;
  }
}

// x[c][h][w] fp32 -> xT[h*256+w][c] fp16, for 2 batches starting at b0.
// Reads coalesced (256B/instr); 16B/lane writes at 128B stride are completed
// to full segments by the other waves' channel chunks (L2 merges).
__global__ __launch_bounds__(256) void xpose(
    const float* __restrict__ x, f16* __restrict__ xT, int b0) {
  int t = threadIdx.x, lane = t & 63, cq = t >> 6;
  int blk = blockIdx.x;
  int bl = blk >> 10;                  // batch within pair
  int rem = blk & 1023;
  int h = rem >> 2, w0 = (rem & 3) << 6;
  int w = w0 + lane, c0 = cq << 4;
  const float* xb = x + (((size_t)(b0 + bl)) << 6) * HW + (size_t)h * 256 + w;
  float v[16];
#pragma unroll
  for (int j = 0; j < 16; ++j) v[j] = xb[(size_t)(c0 + j) * HW];
  f16x8 a, b;
#pragma unroll
  for (int j = 0; j < 8; ++j) { a[j] = (f16)v[j]; b[j] = (f16)v[8 + j]; }
  f16* dst = xT + (((size_t)bl * HW + (size_t)h * 256 + w) << 6) + c0;
  *(f16x8*)dst = a;
  *(f16x8*)(dst + 8) = b;
}

// Fused per 64-pixel tile (one b,h, 64 w): conv A-tile -> MFMA offset conv ->
// bilinear sample*mask (pk fp16) -> MFMA einsum -> +b_dcn -> BN partials ->
// coalesced pre-BN store. 256 thr = 4 waves; wave q owns channel/out chunk q.
__global__ __launch_bounds__(256, 5) void dcn_fused(
    const f16* __restrict__ xT, const f16* __restrict__ wtO,
    const float* __restrict__ b_off, const f16* __restrict__ wtH,
    const float* __restrict__ b_dcn, float* __restrict__ out,
    float* __restrict__ part, int b0) {
  __shared__ __align__(16) unsigned char lds[25600 + 4352];
  f16*   sA   = (f16*)lds;              // [64][200] fp16 A-tile
  float* sOut = (float*)lds;            // [64][65] f32, aliases sA (sA dead)
  float* sOM  = (float*)(lds + 25600);  // [64][17] f32 conv output

  const int t = threadIdx.x, lane = t & 63, cq = t >> 6;
  const int p = lane, c0 = cq << 4;
  const int lrow = lane & 15, lq = lane >> 4, kgrp = lq << 3;

  // XCD swizzle: XCD (blk&7) gets a contiguous g-range
  int g = ((blockIdx.x & 7) << 8) | (blockIdx.x >> 3);
  int bl = g >> 10;
  int rem = g & 1023;
  int h = rem >> 2, w0 = (rem & 3) << 6, w = w0 + p;
  int b = b0 + bl;
  const f16* xb = xT + (((size_t)bl * HW) << 6);

  // ---- Phase 1: un-offset x tile -> sA (zeros for pad rows) ----
#pragma unroll
  for (int kh = 0; kh < 3; ++kh) {
    int hr = h + kh - 1;                        // x row
    f16x8 u0 = splat8(0.f), u1 = splat8(0.f);
    if (hr >= 0 && hr < 256) {                  // block-uniform branch
      const f16* src = xb + (((size_t)(hr * 256 + w)) << 6) + c0;
      u0 = *(const f16x8*)src;
      u1 = *(const f16x8*)(src + 8);
    }
    *(f16x8*)(sA + p * 200 + kh * 64 + c0) = u0;
    *(f16x8*)(sA + p * 200 + kh * 64 + c0 + 8) = u1;
  }
  __syncthreads();

  // ---- Phase 2: offset conv via MFMA; wave q computes pixels 16q..16q+15 ----
  f32x4 accO = {0.f, 0.f, 0.f, 0.f};
#pragma unroll
  for (int kt = 0; kt < 6; ++kt) {
    f16x8 Af = *(const f16x8*)(sA + (c0 + lrow) * 200 + kt * 32 + kgrp);
    f16x8 Bo = *(const f16x8*)(wtO + lrow * 192 + kt * 32 + kgrp);
    accO = __builtin_amdgcn_mfma_f32_16x16x32_f16(Af, Bo, accO, 0, 0, 0);
  }
#pragma unroll
  for (int r = 0; r < 4; ++r)
    sOM[(c0 + lq * 4 + r) * 17 + lrow] = accO[r];   // C: col=lane&15,row=lq*4+r
  __syncthreads();

  float om[9];
#pragma unroll
  for (int o = 0; o < 9; ++o) om[o] = sOM[p * 17 + o] + b_off[o];

  // ---- Phase 3: bilinear sample * mask -> sA[p][kh*64+c] fp16 ----
#pragma unroll
  for (int kh = 0; kh < 3; ++kh) {
    float m = 1.f / (1.f + __expf(-om[6 + kh]));
    float yf = (float)(h + kh) + om[kh];        // xp coords
    float xf = (float)w + om[3 + kh];
    float y0f = floorf(yf), x0f = floorf(xf);
    int iy0 = (int)y0f, ix0 = (int)x0f;
    float wy1 = yf - y0f, wy0 = 1.f - wy1;
    float wx1 = xf - x0f, wx0 = 1.f - wx1;
    int r0 = iy0 - 1, r1 = iy0, g0 = ix0, g1 = ix0 + 1;   // x rows/cols
    bool vr0 = (r0 >= 0) & (r0 < 256), vr1 = (r1 >= 0) & (r1 < 256);
    bool vc0 = (g0 >= 0) & (g0 < 256), vc1 = (g1 >= 0) & (g1 < 256);
    float w00 = (vr0 & vc0) ? wy0 * wx0 * m : 0.f;
    float w01 = (vr0 & vc1) ? wy0 * wx1 * m : 0.f;
    float w10 = (vr1 & vc0) ? wy1 * wx0 * m : 0.f;
    float w11 = (vr1 & vc1) ? wy1 * wx1 * m : 0.f;
    int cr0 = min(max(r0, 0), 255), cr1 = min(max(r1, 0), 255);
    int cg0 = min(max(g0, 0), 255), cg1 = min(max(g1, 0), 255);
    const f16* t00p = xb + (((size_t)(cr0 * 256 + cg0)) << 6) + c0;
    const f16* t01p = xb + (((size_t)(cr0 * 256 + cg1)) << 6) + c0;
    const f16* t10p = xb + (((size_t)(cr1 * 256 + cg0)) << 6) + c0;
    const f16* t11p = xb + (((size_t)(cr1 * 256 + cg1)) << 6) + c0;
    // 8 independent 16B loads (MLP), then packed-fp16 interp
    f16x8 a00 = *(const f16x8*)t00p, b00 = *(const f16x8*)(t00p + 8);
    f16x8 a01 = *(const f16x8*)t01p, b01 = *(const f16x8*)(t01p + 8);
    f16x8 a10 = *(const f16x8*)t10p, b10 = *(const f16x8*)(t10p + 8);
    f16x8 a11 = *(const f16x8*)t11p, b11 = *(const f16x8*)(t11p + 8);
    f16x8 W00 = splat8(w00), W01 = splat8(w01);
    f16x8 W10 = splat8(w10), W11 = splat8(w11);
    f16x8 s0 = a00 * W00 + a01 * W01 + a10 * W10 + a11 * W11;
    f16x8 s1 = b00 * W00 + b01 * W01 + b10 * W10 + b11 * W11;
    *(f16x8*)(sA + p * 200 + kh * 64 + c0) = s0;
    *(f16x8*)(sA + p * 200 + kh * 64 + c0 + 8) = s1;
  }

  // B-fragments (wave's 16 output channels) + bias, before the barrier
  const int nrow = c0 + lrow;                  // output channel o
  f16x8 Bf[6];
#pragma unroll
  for (int kt = 0; kt < 6; ++kt)
    Bf[kt] = *(const f16x8*)(wtH + nrow * 192 + kt * 32 + kgrp);
  float bdc = b_dcn[nrow];
  __syncthreads();

  // ---- Phase 4: MFMA 64x64 += S(64x192) * W(192x64) ----
  f32x4 acc[4];
#pragma unroll
  for (int mt = 0; mt < 4; ++mt) acc[mt] = (f32x4){0.f, 0.f, 0.f, 0.f};
#pragma unroll
  for (int kt = 0; kt < 6; ++kt) {
#pragma unroll
    for (int mt = 0; mt < 4; ++mt) {
      f16x8 Af = *(const f16x8*)(sA + (mt * 16 + lrow) * 200 + kt * 32 + kgrp);
      acc[mt] = __builtin_amdgcn_mfma_f32_16x16x32_f16(Af, Bf[kt], acc[mt],
                                                       0, 0, 0);
    }
  }
  __syncthreads();   // sA dead; reuse as sOut

  // ---- Phase 5: C frags -> sOut + BN partials from registers ----
  float s1 = 0.f, s2 = 0.f;
#pragma unroll
  for (int mt = 0; mt < 4; ++mt) {
    int prow = mt * 16 + lq * 4;
#pragma unroll
    for (int r = 0; r < 4; ++r) {
      float v = acc[mt][r] + bdc;
      sOut[(prow + r) * 65 + nrow] = v;
      s1 += v;
      s2 += v * v;
    }
  }
  s1 += __shfl_xor(s1, 16); s1 += __shfl_xor(s1, 32);
  s2 += __shfl_xor(s2, 16); s2 += __shfl_xor(s2, 32);
  if (lq == 0) {
    size_t slot = (size_t)(b0 >> 1) * 2048 + blockIdx.x;
    part[(size_t)nrow * NBLK + slot] = s1;
    part[(size_t)(64 + nrow) * NBLK + slot] = s2;
  }
  __syncthreads();

  // ---- Phase 6: coalesced pre-BN store (lane = w) ----
  float* ob = out + (((size_t)b) << 6) * HW + (size_t)h * 256 + w0;
#pragma unroll
  for (int i = 0; i < 16; ++i) {
    int o = c0 + i;
    ob[(size_t)o * HW + p] = sOut[p * 65 + o];
  }
}

// part[j][0..8191] -> sums[j], j in [0,128)
__global__ __launch_bounds__(256) void reduce_sums(
    const float* __restrict__ part, float* __restrict__ sums) {
  int j = blockIdx.x;
  const float4* p4 = (const float4*)(part + (size_t)j * NBLK);
  float s = 0.f;
  for (int i = threadIdx.x; i < NBLK / 4; i += 256) {
    float4 v = p4[i];
    s += v.x + v.y + v.z + v.w;
  }
#pragma unroll
  for (int off = 32; off > 0; off >>= 1) s += __shfl_down(s, off);
  __shared__ float ls[4];
  int wid = threadIdx.x >> 6, ln = threadIdx.x & 63;
  if (ln == 0) ls[wid] = s;
  __syncthreads();
  if (threadIdx.x == 0) sums[j] = ls[0] + ls[1] + ls[2] + ls[3];
}

// In-place: out = relu((out-mean)*rsqrt(var+eps)*gamma + beta)
__global__ __launch_bounds__(256) void bn_apply(
    float* __restrict__ out, const float* __restrict__ sums,
    const float* __restrict__ gamma, const float* __restrict__ beta) {
  int blk = blockIdx.x;            // 2048 = 512 planes x 4 quarters
  int pl = blk >> 2, q = blk & 3;
  int o = pl & 63;
  float mean = sums[o] * (1.f / (float)NPER);
  float var = sums[64 + o] * (1.f / (float)NPER) - mean * mean;
  float inv = rsqrtf(var + 1e-5f);
  float sc = gamma[o] * inv;
  float sh = beta[o] - mean * sc;
  float4* base = (float4*)(out + (size_t)pl * HW + q * 16384);
  for (int i = threadIdx.x; i < 4096; i += 256) {
    float4 v = base[i];
    v.x = fmaxf(fmaf(v.x, sc, sh), 0.f);
    v.y = fmaxf(fmaf(v.y, sc, sh), 0.f);
    v.z = fmaxf(fmaf(v.z, sc, sh), 0.f);
    v.w = fmaxf(fmaf(v.w, sc, sh), 0.f);
    base[i] = v;
  }
}

extern "C" void kernel_launch(void* const* d_in, const int* in_sizes, int n_in,
                              void* d_out, int out_size, void* d_ws, size_t ws_size,
                              hipStream_t stream) {
  const float* x     = (const float*)d_in[0];
  const float* w_off = (const float*)d_in[1];
  const float* b_off = (const float*)d_in[2];
  const float* w_dcn = (const float*)d_in[3];
  const float* b_dcn = (const float*)d_in[4];
  const float* gamma = (const float*)d_in[5];
  const float* beta  = (const float*)d_in[6];
  float* out = (float*)d_out;
  float* ws  = (float*)d_ws;

  float* sums = ws + SUMS_OFF;
  f16*   wtO  = (f16*)(ws + WTO_OFF);
  f16*   wtH  = (f16*)(ws + WTH_OFF);
  float* part = ws + PART_OFF;
  f16*   xT   = (f16*)(ws + XT_OFF);

  prep_wts<<<48, 256, 0, stream>>>(w_off, w_dcn, wtO, wtH);
  for (int pair = 0; pair < 4; ++pair) {
    int b0 = pair * 2;
    xpose<<<2048, 256, 0, stream>>>(x, xT, b0);
    dcn_fused<<<2048, 256, 0, stream>>>(xT, wtO, b_off, wtH, b_dcn, out,
                                        part, b0);
  }
  reduce_sums<<<128, 256, 0, stream>>>(part, sums);
  bn_apply<<<2048, 256, 0, stream>>>(out, sums, gamma, beta);
}

// Round 5
// 388.856 us; speedup vs baseline: 1.6222x; 1.2005x over previous
//
#include <hip/hip_runtime.h>
#include <cmath>

// B=8, C=64, H=256, W=256, k=3, pad=1 (H only)
#define HW 65536
#define NPER 524288   // B*H*W per channel for BN
#define NBLK 8192     // dcn_fused grid (one block = 64 pixels)

typedef _Float16 f16;
typedef __attribute__((ext_vector_type(8))) _Float16 f16x8;
typedef __attribute__((ext_vector_type(4))) float f32x4;

__device__ __forceinline__ f16x8 splat8(float v) {
  f16 h = (f16)v;
  f16x8 r = {h, h, h, h, h, h, h, h};
  return r;
}

// ws layout (floats):
//  sums @0       : 128
//  wtO  @128     : 3072 halves  [16 n][192 k] fp16 (n>=9 zeroed)
//  wtH  @1664    : 12288 halves [64 o][192 k] fp16
//  part @7808    : 128*8192 BN partials
//  xT   @1056384 : 8 batches * 65536 px * 64 ch halves = 67 MB
#define SUMS_OFF 0
#define WTO_OFF  128
#define WTH_OFF  1664
#define PART_OFF 7808
#define XT_OFF   1056384

__global__ __launch_bounds__(256) void prep_wts(
    const float* __restrict__ w_off, const float* __restrict__ w_dcn,
    f16* __restrict__ wtO, f16* __restrict__ wtH) {
  int i = blockIdx.x * 256 + threadIdx.x;
  if (i < 12288) {
    int o = i / 192, k = i - o * 192, kh = k >> 6, c = k & 63;
    wtH[i] = (f16)w_dcn[(o * 64 + c) * 3 + kh];
  }
  if (i < 3072) {
    int n = i / 192, k = i - n * 192, kh = k >> 6, c = k & 63;
    wtO[i] = (n < 9) ? (f16)w_off[(n * 64 + c) * 3 + kh] : (f16)0.f;
  }
}

// x[b][c][h][w] fp32 -> xT[b][h*256+w][c] fp16 (all 8 batches)
__global__ __launch_bounds__(256) void xpose(
    const float* __restrict__ x, f16* __restrict__ xT) {
  int t = threadIdx.x, lane = t & 63, cq = t >> 6;
  int blk = blockIdx.x;
  int b = blk >> 10;
  int rem = blk & 1023;
  int h = rem >> 2, w0 = (rem & 3) << 6;
  int w = w0 + lane, c0 = cq << 4;
  const float* xb = x + (((size_t)b) << 6) * HW + (size_t)h * 256 + w;
  float v[16];
#pragma unroll
  for (int j = 0; j < 16; ++j) v[j] = xb[(size_t)(c0 + j) * HW];
  f16x8 a, bb;
#pragma unroll
  for (int j = 0; j < 8; ++j) { a[j] = (f16)v[j]; bb[j] = (f16)v[8 + j]; }
  f16* dst = xT + (((size_t)b * HW + (size_t)h * 256 + w) << 6) + c0;
  *(f16x8*)dst = a;
  *(f16x8*)(dst + 8) = bb;
}

// Fused per 64-pixel tile (one b,h, 64 w):
//  A) conv A-frags direct from xT -> MFMA offset-conv -> sOM (+b_off)
//  B) bilinear sample*mask, 8 lanes/pixel (full-line loads) -> sA fp16
//  C) MFMA einsum 64px x 64out x K=192
//  D) +b_dcn, BN partials, sOut[o][66] via b128
//  E) coalesced pre-BN store
__global__ __launch_bounds__(256, 4) void dcn_fused(
    const f16* __restrict__ xT, const f16* __restrict__ wtO,
    const float* __restrict__ b_off, const f16* __restrict__ wtH,
    const float* __restrict__ b_dcn, float* __restrict__ out,
    float* __restrict__ part) {
  __shared__ __align__(16) unsigned char lds[25600 + 4352];
  f16*   sA   = (f16*)lds;              // [64 px][200] fp16 S-tile
  float* sOut = (float*)lds;            // [64 o][66] f32, aliases sA
  float* sOM  = (float*)(lds + 25600);  // [64 px][17] f32 conv out (+b_off)

  const int t = threadIdx.x, lane = t & 63, cq = t >> 6;
  const int c0 = cq << 4;
  const int lrow = lane & 15, lq = lane >> 4, kgrp = lq << 3;
  const int pix8 = lane >> 3, chunk = lane & 7;   // phase-B mapping

  // XCD swizzle: XCD (blk&7) owns batch b = blk&7's image (L2 locality)
  int g = ((blockIdx.x & 7) << 10) | (blockIdx.x >> 3);
  int b = g >> 10;
  int rem = g & 1023;
  int h = rem >> 2, w0 = (rem & 3) << 6;
  const f16* xb = xT + (((size_t)b * HW) << 6);

  // ---- Phase A: offset conv. A-frag rows = pixels c0..c0+15, direct load ----
  f16x8 Ac[6];
#pragma unroll
  for (int kt = 0; kt < 6; ++kt) {
    int hr = h + (kt >> 1) - 1;                 // x row for this k-chunk
    int hc = min(max(hr, 0), 255);
    int cb = ((kt & 1) << 5) + kgrp;
    const f16* src = xb + (((size_t)(hc * 256 + w0 + c0 + lrow)) << 6) + cb;
    f16x8 v = *(const f16x8*)src;
    if (!(hr >= 0 && hr < 256)) v = splat8(0.f); // wave-uniform pad mask
    Ac[kt] = v;
  }
  f32x4 accO = {0.f, 0.f, 0.f, 0.f};
#pragma unroll
  for (int kt = 0; kt < 6; ++kt) {
    f16x8 Bo = *(const f16x8*)(wtO + lrow * 192 + kt * 32 + kgrp);
    accO = __builtin_amdgcn_mfma_f32_16x16x32_f16(Ac[kt], Bo, accO, 0, 0, 0);
  }
  float boffv = (lrow < 9) ? b_off[lrow] : 0.f;
#pragma unroll
  for (int r = 0; r < 4; ++r)
    sOM[(c0 + lq * 4 + r) * 17 + lrow] = accO[r] + boffv;
  __syncthreads();

  // ---- Phase B: sample. lane = pix8*8+chunk; 2 halves of 8 pixels ----
#pragma unroll
  for (int kh = 0; kh < 3; ++kh) {
#pragma unroll
    for (int half = 0; half < 2; ++half) {
      int pix = c0 + half * 8 + pix8;           // pixel in tile (w = w0+pix)
      float dy   = sOM[pix * 17 + kh];
      float dxv  = sOM[pix * 17 + 3 + kh];
      float mpre = sOM[pix * 17 + 6 + kh];
      float m = 1.f / (1.f + __expf(-mpre));
      float yf = (float)(h + kh) + dy;          // xp coords
      float xf = (float)(w0 + pix) + dxv;
      float y0f = floorf(yf), x0f = floorf(xf);
      int iy0 = (int)y0f, ix0 = (int)x0f;
      float wy1 = yf - y0f, wy0 = 1.f - wy1;
      float wx1 = xf - x0f, wx0 = 1.f - wx1;
      int r0 = iy0 - 1, r1 = iy0, g0 = ix0, g1 = ix0 + 1;  // x rows/cols
      bool vr0 = (r0 >= 0) & (r0 < 256), vr1 = (r1 >= 0) & (r1 < 256);
      bool vc0 = (g0 >= 0) & (g0 < 256), vc1 = (g1 >= 0) & (g1 < 256);
      float w00 = (vr0 & vc0) ? wy0 * wx0 * m : 0.f;
      float w01 = (vr0 & vc1) ? wy0 * wx1 * m : 0.f;
      float w10 = (vr1 & vc0) ? wy1 * wx0 * m : 0.f;
      float w11 = (vr1 & vc1) ? wy1 * wx1 * m : 0.f;
      int cr0 = min(max(r0, 0), 255), cr1 = min(max(r1, 0), 255);
      int cg0 = min(max(g0, 0), 255), cg1 = min(max(g1, 0), 255);
      int cb8 = chunk << 3;                     // channel base for this lane
      const f16* t00p = xb + (((size_t)(cr0 * 256 + cg0)) << 6) + cb8;
      const f16* t01p = xb + (((size_t)(cr0 * 256 + cg1)) << 6) + cb8;
      const f16* t10p = xb + (((size_t)(cr1 * 256 + cg0)) << 6) + cb8;
      const f16* t11p = xb + (((size_t)(cr1 * 256 + cg1)) << 6) + cb8;
      f16x8 a00 = *(const f16x8*)t00p;
      f16x8 a01 = *(const f16x8*)t01p;
      f16x8 a10 = *(const f16x8*)t10p;
      f16x8 a11 = *(const f16x8*)t11p;
      f16x8 s = a00 * splat8(w00) + a01 * splat8(w01) +
                a10 * splat8(w10) + a11 * splat8(w11);
      *(f16x8*)(sA + pix * 200 + kh * 64 + cb8) = s;
    }
  }

  // B-fragments (wave's 16 output channels) + bias, before the barrier
  const int nrow = c0 + lrow;                   // output channel o
  f16x8 Bf[6];
#pragma unroll
  for (int kt = 0; kt < 6; ++kt)
    Bf[kt] = *(const f16x8*)(wtH + nrow * 192 + kt * 32 + kgrp);
  float bdc = b_dcn[nrow];
  __syncthreads();

  // ---- Phase C: MFMA 64x64 += S(64x192) * W(192x64) ----
  f32x4 acc[4];
#pragma unroll
  for (int mt = 0; mt < 4; ++mt) acc[mt] = (f32x4){0.f, 0.f, 0.f, 0.f};
#pragma unroll
  for (int kt = 0; kt < 6; ++kt) {
#pragma unroll
    for (int mt = 0; mt < 4; ++mt) {
      f16x8 Af = *(const f16x8*)(sA + (mt * 16 + lrow) * 200 + kt * 32 + kgrp);
      acc[mt] = __builtin_amdgcn_mfma_f32_16x16x32_f16(Af, Bf[kt], acc[mt],
                                                       0, 0, 0);
    }
  }
  __syncthreads();   // sA dead; reuse as sOut

  // ---- Phase D: +bias, BN partials, sOut[o][66] (b128 writes) ----
  float s1 = 0.f, s2 = 0.f;
#pragma unroll
  for (int mt = 0; mt < 4; ++mt) {
    int prow = mt * 16 + lq * 4;                // pixel of acc[mt][0]
    f32x4 vv;
#pragma unroll
    for (int r = 0; r < 4; ++r) {
      float v = acc[mt][r] + bdc;
      vv[r] = v;
      s1 += v;
      s2 += v * v;
    }
    *(f32x4*)(sOut + nrow * 66 + prow) = vv;    // 4 consecutive pixels
  }
  s1 += __shfl_xor(s1, 16); s1 += __shfl_xor(s1, 32);
  s2 += __shfl_xor(s2, 16); s2 += __shfl_xor(s2, 32);
  if (lq == 0) {
    part[(size_t)nrow * NBLK + blockIdx.x] = s1;
    part[(size_t)(64 + nrow) * NBLK + blockIdx.x] = s2;
  }
  __syncthreads();

  // ---- Phase E: coalesced pre-BN store (lane = w) ----
  float* ob = out + (((size_t)b) << 6) * HW + (size_t)h * 256 + w0;
#pragma unroll
  for (int i = 0; i < 16; ++i) {
    int o = c0 + i;
    ob[(size_t)o * HW + lane] = sOut[o * 66 + lane];
  }
}

// part[j][0..8191] -> sums[j], j in [0,128)
__global__ __launch_bounds__(256) void reduce_sums(
    const float* __restrict__ part, float* __restrict__ sums) {
  int j = blockIdx.x;
  const float4* p4 = (const float4*)(part + (size_t)j * NBLK);
  float s = 0.f;
  for (int i = threadIdx.x; i < NBLK / 4; i += 256) {
    float4 v = p4[i];
    s += v.x + v.y + v.z + v.w;
  }
#pragma unroll
  for (int off = 32; off > 0; off >>= 1) s += __shfl_down(s, off);
  __shared__ float ls[4];
  int wid = threadIdx.x >> 6, ln = threadIdx.x & 63;
  if (ln == 0) ls[wid] = s;
  __syncthreads();
  if (threadIdx.x == 0) sums[j] = ls[0] + ls[1] + ls[2] + ls[3];
}

// In-place: out = relu((out-mean)*rsqrt(var+eps)*gamma + beta)
__global__ __launch_bounds__(256) void bn_apply(
    float* __restrict__ out, const float* __restrict__ sums,
    const float* __restrict__ gamma, const float* __restrict__ beta) {
  int blk = blockIdx.x;            // 2048 = 512 planes x 4 quarters
  int pl = blk >> 2, q = blk & 3;
  int o = pl & 63;
  float mean = sums[o] * (1.f / (float)NPER);
  float var = sums[64 + o] * (1.f / (float)NPER) - mean * mean;
  float inv = rsqrtf(var + 1e-5f);
  float sc = gamma[o] * inv;
  float sh = beta[o] - mean * sc;
  float4* base = (float4*)(out + (size_t)pl * HW + q * 16384);
  for (int i = threadIdx.x; i < 4096; i += 256) {
    float4 v = base[i];
    v.x = fmaxf(fmaf(v.x, sc, sh), 0.f);
    v.y = fmaxf(fmaf(v.y, sc, sh), 0.f);
    v.z = fmaxf(fmaf(v.z, sc, sh), 0.f);
    v.w = fmaxf(fmaf(v.w, sc, sh), 0.f);
    base[i] = v;
  }
}

extern "C" void kernel_launch(void* const* d_in, const int* in_sizes, int n_in,
                              void* d_out, int out_size, void* d_ws, size_t ws_size,
                              hipStream_t stream) {
  const float* x     = (const float*)d_in[0];
  const float* w_off = (const float*)d_in[1];
  const float* b_off = (const float*)d_in[2];
  const float* w_dcn = (const float*)d_in[3];
  const float* b_dcn = (const float*)d_in[4];
  const float* gamma = (const float*)d_in[5];
  const float* beta  = (const float*)d_in[6];
  float* out = (float*)d_out;
  float* ws  = (float*)d_ws;

  float* sums = ws + SUMS_OFF;
  f16*   wtO  = (f16*)(ws + WTO_OFF);
  f16*   wtH  = (f16*)(ws + WTH_OFF);
  float* part = ws + PART_OFF;
  f16*   xT   = (f16*)(ws + XT_OFF);

  prep_wts<<<48, 256, 0, stream>>>(w_off, w_dcn, wtO, wtH);
  xpose<<<8192, 256, 0, stream>>>(x, xT);
  dcn_fused<<<NBLK, 256, 0, stream>>>(xT, wtO, b_off, wtH, b_dcn, out, part);
  reduce_sums<<<128, 256, 0, stream>>>(part, sums);
  bn_apply<<<2048, 256, 0, stream>>>(out, sums, gamma, beta);
}

// Round 6
// 387.150 us; speedup vs baseline: 1.6293x; 1.0044x over previous
//
#include <hip/hip_runtime.h>
#include <cmath>

// B=8, C=64, H=256, W=256, k=3, pad=1 (H only)
#define HW 65536
#define NPER 524288   // B*H*W per channel for BN
#define NBLK 8192     // dcn_fused grid (one block = 64 pixels)

typedef _Float16 f16;
typedef __attribute__((ext_vector_type(8))) _Float16 f16x8;
typedef __attribute__((ext_vector_type(4))) float f32x4;

__device__ __forceinline__ f16x8 splat8(f16 h) {
  f16x8 r = {h, h, h, h, h, h, h, h};
  return r;
}

// ws layout (floats):
//  sums  @0        : 128
//  wtO   @128      : 3072 halves  [16 n][192 k] fp16 (n>=9 zeroed)
//  wtH   @1664     : 12288 halves [64 o][192 k] fp16
//  part  @7808     : 128*8192 BN partials
//  xT    @1056384  : 8 b * 65536 px * 64 ch halves (67 MB)
//  out16 @17833600 : 8 b * 64 o * 65536 px halves (67 MB, pre-BN)
#define SUMS_OFF  0
#define WTO_OFF   128
#define WTH_OFF   1664
#define PART_OFF  7808
#define XT_OFF    1056384
#define OUT16_OFF 17833600

__global__ __launch_bounds__(256) void prep_wts(
    const float* __restrict__ w_off, const float* __restrict__ w_dcn,
    f16* __restrict__ wtO, f16* __restrict__ wtH) {
  int i = blockIdx.x * 256 + threadIdx.x;
  if (i < 12288) {
    int o = i / 192, k = i - o * 192, kh = k >> 6, c = k & 63;
    wtH[i] = (f16)w_dcn[(o * 64 + c) * 3 + kh];
  }
  if (i < 3072) {
    int n = i / 192, k = i - n * 192, kh = k >> 6, c = k & 63;
    wtO[i] = (n < 9) ? (f16)w_off[(n * 64 + c) * 3 + kh] : (f16)0.f;
  }
}

// x[b][c][h][w] fp32 -> xT[b][h*256+w][c] fp16 (all 8 batches)
__global__ __launch_bounds__(256) void xpose(
    const float* __restrict__ x, f16* __restrict__ xT) {
  int t = threadIdx.x, lane = t & 63, cq = t >> 6;
  int blk = blockIdx.x;
  int b = blk >> 10;
  int rem = blk & 1023;
  int h = rem >> 2, w0 = (rem & 3) << 6;
  int w = w0 + lane, c0 = cq << 4;
  const float* xb = x + (((size_t)b) << 6) * HW + (size_t)h * 256 + w;
  float v[16];
#pragma unroll
  for (int j = 0; j < 16; ++j) v[j] = xb[(size_t)(c0 + j) * HW];
  f16x8 a, bb;
#pragma unroll
  for (int j = 0; j < 8; ++j) { a[j] = (f16)v[j]; bb[j] = (f16)v[8 + j]; }
  f16* dst = xT + (((size_t)b * HW + (size_t)h * 256 + w) << 6) + c0;
  *(f16x8*)dst = a;
  *(f16x8*)(dst + 8) = bb;
}

// Fused per 64-pixel tile (one b,h, 64 w):
//  A) conv A-frags direct from xT -> MFMA offset-conv -> sOM (+b_off)
//  W) 192 threads: per (px,kh) sigmoid/floor/valid -> f16 weights + short
//     row/col taps in LDS (aliases sOM; 2 extra barriers)
//  B) bilinear sample: 8 lanes/pixel, broadcast LDS params, pk-fp16 FMA
//  C) MFMA einsum 64px x 64out x K=192
//  D) +b_dcn, BN partials from registers, sOut[o][66] via b128
//  E) pre-BN store as fp16 (out16)
__global__ __launch_bounds__(256, 5) void dcn_fused(
    const f16* __restrict__ xT, const f16* __restrict__ wtO,
    const float* __restrict__ b_off, const f16* __restrict__ wtH,
    const float* __restrict__ b_dcn, f16* __restrict__ out16,
    float* __restrict__ part) {
  __shared__ __align__(16) unsigned char lds[30208];
  f16*   sA   = (f16*)lds;                             // [64 px][200] fp16
  float* sOut = (float*)lds;                           // [64 o][66] f32 (alias)
  float* sOM  = (float*)(lds + 25600);                 // [64 px][17] f32
  unsigned short* sWo = (unsigned short*)(lds + 25600);// [192][4] r0,r1,c0,c1
  f16*   sWw  = (f16*)(lds + 27136);                   // [192][4] w00..w11

  const int t = threadIdx.x, lane = t & 63, cq = t >> 6;
  const int c0 = cq << 4;
  const int lrow = lane & 15, lq = lane >> 4, kgrp = lq << 3;
  const int pix8 = lane >> 3, chunk = lane & 7;        // phase-B mapping
  const int cb8 = chunk << 3;

  // XCD swizzle: XCD (blk&7) owns batch b = blk&7's image (L2 locality)
  int g = ((blockIdx.x & 7) << 10) | (blockIdx.x >> 3);
  int b = g >> 10;
  int rem = g & 1023;
  int h = rem >> 2, w0 = (rem & 3) << 6;
  const f16* xb = xT + (((size_t)b * HW) << 6);

  // ---- Phase A: offset conv. A-frag rows = pixels c0..c0+15, direct load ----
  f16x8 Ac[6];
#pragma unroll
  for (int kt = 0; kt < 6; ++kt) {
    int hr = h + (kt >> 1) - 1;                 // x row for this k-chunk
    int hc = min(max(hr, 0), 255);
    int cb = ((kt & 1) << 5) + kgrp;
    const f16* src = xb + (((size_t)(hc * 256 + w0 + c0 + lrow)) << 6) + cb;
    f16x8 v = *(const f16x8*)src;
    if (!(hr >= 0 && hr < 256)) v = splat8((f16)0.f);  // wave-uniform pad
    Ac[kt] = v;
  }
  f32x4 accO = {0.f, 0.f, 0.f, 0.f};
#pragma unroll
  for (int kt = 0; kt < 6; ++kt) {
    f16x8 Bo = *(const f16x8*)(wtO + lrow * 192 + kt * 32 + kgrp);
    accO = __builtin_amdgcn_mfma_f32_16x16x32_f16(Ac[kt], Bo, accO, 0, 0, 0);
  }
  float boffv = (lrow < 9) ? b_off[lrow] : 0.f;
#pragma unroll
  for (int r = 0; r < 4; ++r)
    sOM[(c0 + lq * 4 + r) * 17 + lrow] = accO[r] + boffv;
  __syncthreads();

  // ---- Phase W: per-(px,kh) interp params -> sWo/sWw (aliases sOM) ----
  float dy = 0.f, dxv = 0.f, mpre = 0.f;
  int px = t & 63, khw = t >> 6;
  if (t < 192) {
    dy   = sOM[px * 17 + khw];
    dxv  = sOM[px * 17 + 3 + khw];
    mpre = sOM[px * 17 + 6 + khw];
  }
  __syncthreads();          // sOM fully read; safe to overwrite with sW*
  if (t < 192) {
    float m = 1.f / (1.f + __expf(-mpre));
    float yf = (float)(h + khw) + dy;           // xp coords
    float xf = (float)(w0 + px) + dxv;
    float y0f = floorf(yf), x0f = floorf(xf);
    int iy0 = (int)y0f, ix0 = (int)x0f;
    float wy1 = yf - y0f, wy0 = 1.f - wy1;
    float wx1 = xf - x0f, wx0 = 1.f - wx1;
    int r0 = iy0 - 1, r1 = iy0, g0 = ix0, g1 = ix0 + 1;  // x rows/cols
    bool vr0 = (r0 >= 0) & (r0 < 256), vr1 = (r1 >= 0) & (r1 < 256);
    bool vc0 = (g0 >= 0) & (g0 < 256), vc1 = (g1 >= 0) & (g1 < 256);
    float w00 = (vr0 & vc0) ? wy0 * wx0 * m : 0.f;
    float w01 = (vr0 & vc1) ? wy0 * wx1 * m : 0.f;
    float w10 = (vr1 & vc0) ? wy1 * wx0 * m : 0.f;
    float w11 = (vr1 & vc1) ? wy1 * wx1 * m : 0.f;
    int e = px * 3 + khw;
    sWo[e * 4 + 0] = (unsigned short)min(max(r0, 0), 255);
    sWo[e * 4 + 1] = (unsigned short)min(max(r1, 0), 255);
    sWo[e * 4 + 2] = (unsigned short)min(max(g0, 0), 255);
    sWo[e * 4 + 3] = (unsigned short)min(max(g1, 0), 255);
    sWw[e * 4 + 0] = (f16)w00;
    sWw[e * 4 + 1] = (f16)w01;
    sWw[e * 4 + 2] = (f16)w10;
    sWw[e * 4 + 3] = (f16)w11;
  }
  __syncthreads();

  // ---- Phase B: sample. lane = pix8*8+chunk; 2 halves of 8 pixels ----
#pragma unroll
  for (int kh = 0; kh < 3; ++kh) {
#pragma unroll
    for (int half = 0; half < 2; ++half) {
      int pix = c0 + half * 8 + pix8;           // pixel in tile
      int e = pix * 3 + kh;
      unsigned short r0 = sWo[e * 4 + 0], r1 = sWo[e * 4 + 1];
      unsigned short g0 = sWo[e * 4 + 2], g1 = sWo[e * 4 + 3];
      f16 w00 = sWw[e * 4 + 0], w01 = sWw[e * 4 + 1];
      f16 w10 = sWw[e * 4 + 2], w11 = sWw[e * 4 + 3];
      const f16* p00 = xb + ((((int)r0 << 8) + g0) << 6) + cb8;
      const f16* p01 = xb + ((((int)r0 << 8) + g1) << 6) + cb8;
      const f16* p10 = xb + ((((int)r1 << 8) + g0) << 6) + cb8;
      const f16* p11 = xb + ((((int)r1 << 8) + g1) << 6) + cb8;
      f16x8 a00 = *(const f16x8*)p00;
      f16x8 a01 = *(const f16x8*)p01;
      f16x8 a10 = *(const f16x8*)p10;
      f16x8 a11 = *(const f16x8*)p11;
      f16x8 s = a00 * splat8(w00) + a01 * splat8(w01) +
                a10 * splat8(w10) + a11 * splat8(w11);
      *(f16x8*)(sA + pix * 200 + kh * 64 + cb8) = s;
    }
  }

  // B-fragments (wave's 16 output channels) + bias, before the barrier
  const int nrow = c0 + lrow;                   // output channel o
  f16x8 Bf[6];
#pragma unroll
  for (int kt = 0; kt < 6; ++kt)
    Bf[kt] = *(const f16x8*)(wtH + nrow * 192 + kt * 32 + kgrp);
  float bdc = b_dcn[nrow];
  __syncthreads();

  // ---- Phase C: MFMA 64x64 += S(64x192) * W(192x64) ----
  f32x4 acc[4];
#pragma unroll
  for (int mt = 0; mt < 4; ++mt) acc[mt] = (f32x4){0.f, 0.f, 0.f, 0.f};
#pragma unroll
  for (int kt = 0; kt < 6; ++kt) {
#pragma unroll
    for (int mt = 0; mt < 4; ++mt) {
      f16x8 Af = *(const f16x8*)(sA + (mt * 16 + lrow) * 200 + kt * 32 + kgrp);
      acc[mt] = __builtin_amdgcn_mfma_f32_16x16x32_f16(Af, Bf[kt], acc[mt],
                                                       0, 0, 0);
    }
  }
  __syncthreads();   // sA dead; reuse as sOut

  // ---- Phase D: +bias, BN partials, sOut[o][66] (b128 writes) ----
  float s1 = 0.f, s2 = 0.f;
#pragma unroll
  for (int mt = 0; mt < 4; ++mt) {
    int prow = mt * 16 + lq * 4;                // pixel of acc[mt][0]
    f32x4 vv;
#pragma unroll
    for (int r = 0; r < 4; ++r) {
      float v = acc[mt][r] + bdc;
      vv[r] = v;
      s1 += v;
      s2 += v * v;
    }
    *(f32x4*)(sOut + nrow * 66 + prow) = vv;    // 4 consecutive pixels
  }
  s1 += __shfl_xor(s1, 16); s1 += __shfl_xor(s1, 32);
  s2 += __shfl_xor(s2, 16); s2 += __shfl_xor(s2, 32);
  if (lq == 0) {
    part[(size_t)nrow * NBLK + blockIdx.x] = s1;
    part[(size_t)(64 + nrow) * NBLK + blockIdx.x] = s2;
  }
  __syncthreads();

  // ---- Phase E: coalesced pre-BN fp16 store (lane = w) ----
  f16* ob = out16 + (((size_t)b) << 6) * HW + (size_t)h * 256 + w0;
#pragma unroll
  for (int i = 0; i < 16; ++i) {
    int o = c0 + i;
    ob[(size_t)o * HW + lane] = (f16)sOut[o * 66 + lane];
  }
}

// part[j][0..8191] -> sums[j], j in [0,128)
__global__ __launch_bounds__(256) void reduce_sums(
    const float* __restrict__ part, float* __restrict__ sums) {
  int j = blockIdx.x;
  const float4* p4 = (const float4*)(part + (size_t)j * NBLK);
  float s = 0.f;
  for (int i = threadIdx.x; i < NBLK / 4; i += 256) {
    float4 v = p4[i];
    s += v.x + v.y + v.z + v.w;
  }
#pragma unroll
  for (int off = 32; off > 0; off >>= 1) s += __shfl_down(s, off);
  __shared__ float ls[4];
  int wid = threadIdx.x >> 6, ln = threadIdx.x & 63;
  if (ln == 0) ls[wid] = s;
  __syncthreads();
  if (threadIdx.x == 0) sums[j] = ls[0] + ls[1] + ls[2] + ls[3];
}

// out = relu((out16-mean)*rsqrt(var+eps)*gamma + beta)  (fp16 in, fp32 out)
__global__ __launch_bounds__(256) void bn_apply(
    const f16* __restrict__ out16, float* __restrict__ out,
    const float* __restrict__ sums, const float* __restrict__ gamma,
    const float* __restrict__ beta) {
  int blk = blockIdx.x;            // 2048 = 512 planes x 4 quarters
  int pl = blk >> 2, q = blk & 3;
  int o = pl & 63;
  float mean = sums[o] * (1.f / (float)NPER);
  float var = sums[64 + o] * (1.f / (float)NPER) - mean * mean;
  float inv = rsqrtf(var + 1e-5f);
  float sc = gamma[o] * inv;
  float sh = beta[o] - mean * sc;
  const f16x8* src = (const f16x8*)(out16 + (size_t)pl * HW + q * 16384);
  float4* dst = (float4*)(out + (size_t)pl * HW + q * 16384);
  for (int i = threadIdx.x; i < 2048; i += 256) {
    f16x8 v = src[i];
    float4 lo, hi;
    lo.x = fmaxf(fmaf((float)v[0], sc, sh), 0.f);
    lo.y = fmaxf(fmaf((float)v[1], sc, sh), 0.f);
    lo.z = fmaxf(fmaf((float)v[2], sc, sh), 0.f);
    lo.w = fmaxf(fmaf((float)v[3], sc, sh), 0.f);
    hi.x = fmaxf(fmaf((float)v[4], sc, sh), 0.f);
    hi.y = fmaxf(fmaf((float)v[5], sc, sh), 0.f);
    hi.z = fmaxf(fmaf((float)v[6], sc, sh), 0.f);
    hi.w = fmaxf(fmaf((float)v[7], sc, sh), 0.f);
    dst[2 * i] = lo;
    dst[2 * i + 1] = hi;
  }
}

extern "C" void kernel_launch(void* const* d_in, const int* in_sizes, int n_in,
                              void* d_out, int out_size, void* d_ws, size_t ws_size,
                              hipStream_t stream) {
  const float* x     = (const float*)d_in[0];
  const float* w_off = (const float*)d_in[1];
  const float* b_off = (const float*)d_in[2];
  const float* w_dcn = (const float*)d_in[3];
  const float* b_dcn = (const float*)d_in[4];
  const float* gamma = (const float*)d_in[5];
  const float* beta  = (const float*)d_in[6];
  float* out = (float*)d_out;
  float* ws  = (float*)d_ws;

  float* sums = ws + SUMS_OFF;
  f16*   wtO  = (f16*)(ws + WTO_OFF);
  f16*   wtH  = (f16*)(ws + WTH_OFF);
  float* part = ws + PART_OFF;
  f16*   xT   = (f16*)(ws + XT_OFF);
  f16*   o16  = (f16*)(ws + OUT16_OFF);

  prep_wts<<<48, 256, 0, stream>>>(w_off, w_dcn, wtO, wtH);
  xpose<<<8192, 256, 0, stream>>>(x, xT);
  dcn_fused<<<NBLK, 256, 0, stream>>>(xT, wtO, b_off, wtH, b_dcn, o16, part);
  reduce_sums<<<128, 256, 0, stream>>>(part, sums);
  bn_apply<<<2048, 256, 0, stream>>>(o16, out, sums, gamma, beta);
}